// Round 3
// baseline (1336.064 us; speedup 1.0000x reference)
//
#include <hip/hip_runtime.h>

// Problem constants
#define HH   1024
#define WW   2048
#define HWP  (HH * WW)          // 2,097,152 pixels
#define CC   34
#define NI   128
#define THING_LO 24
#define THING_HI 33
#define NTC  10                 // thing classes 24..33

// Native vector type for nontemporal stores (HIP float4 is a class -> rejected)
typedef float nfloat4 __attribute__((ext_vector_type(4)));

// Output layout (all float32, concatenated in return order)
#define OFF_CLASS  ((size_t)NI * HWP)
#define OFF_PROBS  (OFF_CLASS + NI)
#define OFF_SEGP   (OFF_PROBS + NI)
#define OFF_TOTAL  (OFF_SEGP + NI)
#define OFF_VALID  (OFF_TOTAL + NI)

// Workspace layout (bytes)
#define WS_COUNTS  0                         // int[NI*NTC] = 5120 B
#define WS_CLS     (NI * NTC * 4)            // int[NI]
#define WS_INV     (WS_CLS + NI * 4)         // float[NI]
#define WS_INST    8192                      // u8[HWP] packed as u32[HWP/4] (2 MB)

__device__ __forceinline__ int thing_inst(int s, int im) {
    return (s >= THING_LO && s <= THING_HI) ? im : 0;
}

// K0: prepass. Reads maps (16.8 MB), emits packed u8 inst array (2 MB) and
// the (inst, thing-class) count histogram via global atomics (~600K adds
// over 1280 addresses).
__global__ __launch_bounds__(256) void k0_prep(
    const int* __restrict__ seg, const int* __restrict__ imap,
    unsigned int* __restrict__ inst_pack, int* __restrict__ counts)
{
    const int t = blockIdx.x * 256 + threadIdx.x;   // 0 .. HWP/4-1
    const int p = t * 4;
    const int4 sg = *reinterpret_cast<const int4*>(seg + p);
    const int4 im = *reinterpret_cast<const int4*>(imap + p);

    const int i0 = thing_inst(sg.x, im.x);
    const int i1 = thing_inst(sg.y, im.y);
    const int i2 = thing_inst(sg.z, im.z);
    const int i3 = thing_inst(sg.w, im.w);

    inst_pack[t] = (unsigned)i0 | ((unsigned)i1 << 8) |
                   ((unsigned)i2 << 16) | ((unsigned)i3 << 24);

    if (i0 > 0) atomicAdd(&counts[(i0 - 1) * NTC + (sg.x - THING_LO)], 1);
    if (i1 > 0) atomicAdd(&counts[(i1 - 1) * NTC + (sg.y - THING_LO)], 1);
    if (i2 > 0) atomicAdd(&counts[(i2 - 1) * NTC + (sg.z - THING_LO)], 1);
    if (i3 > 0) atomicAdd(&counts[(i3 - 1) * NTC + (sg.w - THING_LO)], 1);
}

// K2: one block of 128 threads. argmax over the 10 thing-class counts
// (strict > from low class == jnp.argmax first-max; all-zero row -> class 0).
// Writes small outputs, zeroes out[SEGP] for K3's atomic accumulation, and
// stores cls / 1/max(tot,1) for K3.
__global__ __launch_bounds__(128) void k2_stats(
    const int* __restrict__ counts, const float* __restrict__ iprobs,
    float* __restrict__ out, int* __restrict__ cls_ws, float* __restrict__ inv_ws)
{
    const int i = threadIdx.x;      // 0..127 -> instance id i+1
    int bestv = 0, bestc = 0, tot = 0;
    #pragma unroll
    for (int j = 0; j < NTC; ++j) {
        const int c = counts[i * NTC + j];
        tot += c;
        if (c > bestv) { bestv = c; bestc = THING_LO + j; }
    }
    cls_ws[i] = bestc;
    inv_ws[i] = 1.0f / (float)(tot > 0 ? tot : 1);
    out[OFF_CLASS + i] = (float)bestc;
    out[OFF_PROBS + i] = iprobs[i];
    out[OFF_SEGP  + i] = 0.0f;
    out[OFF_TOTAL + i] = (float)tot;
    out[OFF_VALID + i] = (tot > 0) ? 1.0f : 0.0f;
}

// K_MASK: grid = 128 planes x 64 chunks. Each block writes a 128 KB
// SEQUENTIAL span of one mask plane (good DRAM row locality), reading its
// 32K-pixel inst chunk from the 2 MB packed array (L2-resident, reused 128x).
#define MCHUNK_PX 32768
#define MCHUNKS   (HWP / MCHUNK_PX)   // 64
__global__ __launch_bounds__(256) void k_mask(
    const unsigned int* __restrict__ inst_pack, float* __restrict__ out)
{
    const int plane = blockIdx.x >> 6;          // 0..127
    const int chunk = blockIdx.x & 63;
    const unsigned pid = (unsigned)(plane + 1); // instance id 1..128
    const size_t base_px = (size_t)chunk * MCHUNK_PX;
    float* oplane = out + (size_t)plane * HWP + base_px;
    const unsigned int* ip = inst_pack + (base_px >> 2);

    #pragma unroll 8
    for (int j = 0; j < MCHUNK_PX / (256 * 4); ++j) {   // 32 iters
        const int q = j * 256 + threadIdx.x;            // quad index in chunk
        const unsigned int w = ip[q];
        nfloat4 v;
        v.x = ((w & 255u)         == pid) ? 1.0f : 0.0f;
        v.y = (((w >> 8) & 255u)  == pid) ? 1.0f : 0.0f;
        v.z = (((w >> 16) & 255u) == pid) ? 1.0f : 0.0f;
        v.w = ((w >> 24)          == pid) ? 1.0f : 0.0f;
        __builtin_nontemporal_store(v, reinterpret_cast<nfloat4*>(oplane + q * 4));
    }
}

// K3: gather probs[cls[inst]][pix] for things-pixels via the packed inst
// array; LDS-accumulate per block; flush pre-divided partial into out[SEGP].
__global__ __launch_bounds__(256) void k3_segsum(
    const unsigned int* __restrict__ inst_pack, const float* __restrict__ probs,
    const int* __restrict__ cls_ws, const float* __restrict__ inv_ws,
    float* __restrict__ out)
{
    __shared__ float lsum[NI];
    __shared__ int   scls[NI];
    if (threadIdx.x < NI) {
        lsum[threadIdx.x] = 0.0f;
        scls[threadIdx.x] = cls_ws[threadIdx.x];
    }
    __syncthreads();

    // 512 blocks x 256 threads x 16 px = HWP exactly
    const int t = blockIdx.x * 256 + threadIdx.x;       // 0 .. HWP/16-1
    const uint4 wv = reinterpret_cast<const uint4*>(inst_pack)[t];
    const int base_px = t * 16;
    const unsigned wvs[4] = { wv.x, wv.y, wv.z, wv.w };
    #pragma unroll
    for (int wi = 0; wi < 4; ++wi) {
        const unsigned w = wvs[wi];
        #pragma unroll
        for (int k = 0; k < 4; ++k) {
            const int inst = (int)((w >> (8 * k)) & 255u);
            if (inst > 0) {
                const size_t idx = (size_t)scls[inst - 1] * HWP +
                                   (size_t)(base_px + wi * 4 + k);
                atomicAdd(&lsum[inst - 1], probs[idx]);
            }
        }
    }
    __syncthreads();
    if (threadIdx.x < NI) {
        const float v = lsum[threadIdx.x];
        if (v != 0.0f)
            atomicAdd(&out[OFF_SEGP + threadIdx.x], v * inv_ws[threadIdx.x]);
    }
}

extern "C" void kernel_launch(void* const* d_in, const int* in_sizes, int n_in,
                              void* d_out, int out_size, void* d_ws, size_t ws_size,
                              hipStream_t stream) {
    const int*   seg    = (const int*)d_in[0];     // (H,W) int32
    const int*   imap   = (const int*)d_in[1];     // (H,W) int32
    const float* probs  = (const float*)d_in[2];   // (C,H,W) f32
    const float* iprobs = (const float*)d_in[3];   // (NI,) f32
    float* out = (float*)d_out;

    char* ws = (char*)d_ws;
    int*          counts    = (int*)(ws + WS_COUNTS);
    int*          cls_ws    = (int*)(ws + WS_CLS);
    float*        inv_ws    = (float*)(ws + WS_INV);
    unsigned int* inst_pack = (unsigned int*)(ws + WS_INST);

    (void)hipMemsetAsync(counts, 0, NI * NTC * sizeof(int), stream);

    k0_prep<<<(HWP / 4) / 256, 256, 0, stream>>>(seg, imap, inst_pack, counts);
    k2_stats<<<1, 128, 0, stream>>>(counts, iprobs, out, cls_ws, inv_ws);
    k_mask<<<NI * MCHUNKS, 256, 0, stream>>>(inst_pack, out);
    k3_segsum<<<(HWP / 16) / 256, 256, 0, stream>>>(inst_pack, probs, cls_ws, inv_ws, out);
}

// Round 4
// 1330.002 us; speedup vs baseline: 1.0046x; 1.0046x over previous
//
#include <hip/hip_runtime.h>

// Problem constants
#define HH   1024
#define WW   2048
#define HWP  (HH * WW)          // 2,097,152 pixels
#define CC   34
#define NI   128
#define THING_LO 24
#define THING_HI 33
#define NTC  10                 // thing classes 24..33

// Native vector type for nontemporal stores (HIP float4 is a class -> rejected)
typedef float nfloat4 __attribute__((ext_vector_type(4)));

// Output layout (all float32, concatenated in return order)
#define OFF_CLASS  ((size_t)NI * HWP)
#define OFF_PROBS  (OFF_CLASS + NI)
#define OFF_SEGP   (OFF_PROBS + NI)
#define OFF_TOTAL  (OFF_SEGP + NI)
#define OFF_VALID  (OFF_TOTAL + NI)

// Workspace layout (bytes)
#define WS_COUNTS  0                         // int[NI*NTC] = 5120 B
#define WS_CLS     (NI * NTC * 4)            // int[NI]
#define WS_INV     (WS_CLS + NI * 4)         // float[NI]
#define WS_INST    8192                      // u8[HWP] packed as u32[HWP/4] (2 MB)

#define GATHER_BLOCKS 256
#define MASK_BLOCKS   ((HWP / 4) / 256)      // 2048
#define MERGED_BLOCKS (GATHER_BLOCKS + MASK_BLOCKS)

__device__ __forceinline__ int thing_inst(int s, int im) {
    return (s >= THING_LO && s <= THING_HI) ? im : 0;
}

// K0: prepass. Reads maps (16.8 MB), emits packed u8 inst array (2 MB) and
// the (inst, thing-class) count histogram via global atomics (~600K adds
// spread over 1280 addresses / ~80 cache lines — measured-cheap).
__global__ __launch_bounds__(256) void k0_prep(
    const int* __restrict__ seg, const int* __restrict__ imap,
    unsigned int* __restrict__ inst_pack, int* __restrict__ counts)
{
    const int t = blockIdx.x * 256 + threadIdx.x;   // 0 .. HWP/4-1
    const int p = t * 4;
    const int4 sg = *reinterpret_cast<const int4*>(seg + p);
    const int4 im = *reinterpret_cast<const int4*>(imap + p);

    const int i0 = thing_inst(sg.x, im.x);
    const int i1 = thing_inst(sg.y, im.y);
    const int i2 = thing_inst(sg.z, im.z);
    const int i3 = thing_inst(sg.w, im.w);

    inst_pack[t] = (unsigned)i0 | ((unsigned)i1 << 8) |
                   ((unsigned)i2 << 16) | ((unsigned)i3 << 24);

    if (i0 > 0) atomicAdd(&counts[(i0 - 1) * NTC + (sg.x - THING_LO)], 1);
    if (i1 > 0) atomicAdd(&counts[(i1 - 1) * NTC + (sg.y - THING_LO)], 1);
    if (i2 > 0) atomicAdd(&counts[(i2 - 1) * NTC + (sg.z - THING_LO)], 1);
    if (i3 > 0) atomicAdd(&counts[(i3 - 1) * NTC + (sg.w - THING_LO)], 1);
}

// K2: one block of 128 threads. argmax over the 10 thing-class counts
// (strict > from low class == jnp.argmax first-max; all-zero row -> class 0).
// Writes small outputs, zeroes out[SEGP] for the gather's atomic accumulate,
// stores cls and 1/max(tot,1).
__global__ __launch_bounds__(128) void k2_stats(
    const int* __restrict__ counts, const float* __restrict__ iprobs,
    float* __restrict__ out, int* __restrict__ cls_ws, float* __restrict__ inv_ws)
{
    const int i = threadIdx.x;      // 0..127 -> instance id i+1
    int bestv = 0, bestc = 0, tot = 0;
    #pragma unroll
    for (int j = 0; j < NTC; ++j) {
        const int c = counts[i * NTC + j];
        tot += c;
        if (c > bestv) { bestv = c; bestc = THING_LO + j; }
    }
    cls_ws[i] = bestc;
    inv_ws[i] = 1.0f / (float)(tot > 0 ? tot : 1);
    out[OFF_CLASS + i] = (float)bestc;
    out[OFF_PROBS + i] = iprobs[i];
    out[OFF_SEGP  + i] = 0.0f;
    out[OFF_TOTAL + i] = (float)tot;
    out[OFF_VALID + i] = (tot > 0) ? 1.0f : 0.0f;
}

// MERGED: blocks [0, GATHER_BLOCKS) do the sparse prob gather (latency-bound,
// hides under the write-BW-saturated mask blocks); blocks [GATHER_BLOCKS, ..)
// each write 128 planes x 1 KB nontemporal (R2's proven pattern), reading the
// 2 MB inst_pack instead of 16.8 MB of maps.
__global__ __launch_bounds__(256) void k_merged(
    const unsigned int* __restrict__ inst_pack, const float* __restrict__ probs,
    const int* __restrict__ cls_ws, const float* __restrict__ inv_ws,
    float* __restrict__ out)
{
    __shared__ float lsum[NI];
    __shared__ int   scls[NI];

    if (blockIdx.x >= GATHER_BLOCKS) {
        // ---- mask role ----
        const int t = (blockIdx.x - GATHER_BLOCKS) * 256 + threadIdx.x; // quad idx
        const unsigned w = inst_pack[t];
        const int i0 = (int)(w & 255u);
        const int i1 = (int)((w >> 8) & 255u);
        const int i2 = (int)((w >> 16) & 255u);
        const int i3 = (int)(w >> 24);

        float* o = out + (size_t)t * 4;
        #pragma unroll
        for (int i = 1; i <= NI; ++i) {
            nfloat4 v;
            v.x = (i0 == i) ? 1.0f : 0.0f;
            v.y = (i1 == i) ? 1.0f : 0.0f;
            v.z = (i2 == i) ? 1.0f : 0.0f;
            v.w = (i3 == i) ? 1.0f : 0.0f;
            __builtin_nontemporal_store(v, reinterpret_cast<nfloat4*>(o));
            o += HWP;
        }
    } else {
        // ---- gather role ----
        if (threadIdx.x < NI) {
            lsum[threadIdx.x] = 0.0f;
            scls[threadIdx.x] = cls_ws[threadIdx.x];
        }
        __syncthreads();

        // HWP/16 = 131072 quad16 groups; 256 blocks x 256 threads -> 2 iters
        for (int t = blockIdx.x * 256 + threadIdx.x; t < HWP / 16;
             t += GATHER_BLOCKS * 256) {
            const uint4 wv = reinterpret_cast<const uint4*>(inst_pack)[t];
            const int base_px = t * 16;
            const unsigned wvs[4] = { wv.x, wv.y, wv.z, wv.w };
            #pragma unroll
            for (int wi = 0; wi < 4; ++wi) {
                const unsigned w = wvs[wi];
                #pragma unroll
                for (int k = 0; k < 4; ++k) {
                    const int inst = (int)((w >> (8 * k)) & 255u);
                    if (inst > 0) {
                        const size_t idx = (size_t)scls[inst - 1] * HWP +
                                           (size_t)(base_px + wi * 4 + k);
                        atomicAdd(&lsum[inst - 1], probs[idx]);
                    }
                }
            }
        }
        __syncthreads();
        if (threadIdx.x < NI) {
            const float v = lsum[threadIdx.x];
            if (v != 0.0f)
                atomicAdd(&out[OFF_SEGP + threadIdx.x], v * inv_ws[threadIdx.x]);
        }
    }
}

extern "C" void kernel_launch(void* const* d_in, const int* in_sizes, int n_in,
                              void* d_out, int out_size, void* d_ws, size_t ws_size,
                              hipStream_t stream) {
    const int*   seg    = (const int*)d_in[0];     // (H,W) int32
    const int*   imap   = (const int*)d_in[1];     // (H,W) int32
    const float* probs  = (const float*)d_in[2];   // (C,H,W) f32
    const float* iprobs = (const float*)d_in[3];   // (NI,) f32
    float* out = (float*)d_out;

    char* ws = (char*)d_ws;
    int*          counts    = (int*)(ws + WS_COUNTS);
    int*          cls_ws    = (int*)(ws + WS_CLS);
    float*        inv_ws    = (float*)(ws + WS_INV);
    unsigned int* inst_pack = (unsigned int*)(ws + WS_INST);

    (void)hipMemsetAsync(counts, 0, NI * NTC * sizeof(int), stream);

    k0_prep<<<(HWP / 4) / 256, 256, 0, stream>>>(seg, imap, inst_pack, counts);
    k2_stats<<<1, 128, 0, stream>>>(counts, iprobs, out, cls_ws, inv_ws);
    k_merged<<<MERGED_BLOCKS, 256, 0, stream>>>(inst_pack, probs, cls_ws, inv_ws, out);
}

// Round 5
// 1280.542 us; speedup vs baseline: 1.0434x; 1.0386x over previous
//
#include <hip/hip_runtime.h>

// Problem constants
#define HH   1024
#define WW   2048
#define HWP  (HH * WW)          // 2,097,152 pixels
#define CC   34
#define NI   128
#define THING_LO 24
#define THING_HI 33
#define NTC  10                 // thing classes 24..33

// Native vector type (HIP float4 is a class; keep ext_vector for flexibility)
typedef float nfloat4 __attribute__((ext_vector_type(4)));

// Output layout (all float32, concatenated in return order)
#define OFF_CLASS  ((size_t)NI * HWP)
#define OFF_PROBS  (OFF_CLASS + NI)
#define OFF_SEGP   (OFF_PROBS + NI)
#define OFF_TOTAL  (OFF_SEGP + NI)
#define OFF_VALID  (OFF_TOTAL + NI)

// Workspace layout (bytes)
#define WS_COUNTS  0                         // int[NI*NTC] = 5120 B
#define WS_CLS     (NI * NTC * 4)            // int[NI]
#define WS_INV     (WS_CLS + NI * 4)         // float[NI]

__device__ __forceinline__ int thing_inst(int s, int im) {
    return (s >= THING_LO && s <= THING_HI) ? im : 0;
}

// K1 (R2's proven structure, PLAIN stores): 4 pixels/thread, writes all 128
// mask planes as cached float4 stores (1 KB/wave/plane, full-line coverage,
// L2 write-back bursts like the harness fill), plus fire-and-forget count
// atomics (~600K adds over 1280 addresses, non-blocking).
__global__ __launch_bounds__(256) void k1_mask_count(
    const int* __restrict__ seg, const int* __restrict__ imap,
    float* __restrict__ out_masks, int* __restrict__ counts)
{
    const int t = blockIdx.x * 256 + threadIdx.x;   // 0 .. HWP/4-1
    const int p = t * 4;
    const int4 sg = *reinterpret_cast<const int4*>(seg + p);
    const int4 im = *reinterpret_cast<const int4*>(imap + p);

    const int i0 = thing_inst(sg.x, im.x);
    const int i1 = thing_inst(sg.y, im.y);
    const int i2 = thing_inst(sg.z, im.z);
    const int i3 = thing_inst(sg.w, im.w);

    if (i0 > 0) atomicAdd(&counts[(i0 - 1) * NTC + (sg.x - THING_LO)], 1);
    if (i1 > 0) atomicAdd(&counts[(i1 - 1) * NTC + (sg.y - THING_LO)], 1);
    if (i2 > 0) atomicAdd(&counts[(i2 - 1) * NTC + (sg.z - THING_LO)], 1);
    if (i3 > 0) atomicAdd(&counts[(i3 - 1) * NTC + (sg.w - THING_LO)], 1);

    float* o = out_masks + p;
    #pragma unroll
    for (int i = 1; i <= NI; ++i) {
        nfloat4 v;
        v.x = (i0 == i) ? 1.0f : 0.0f;
        v.y = (i1 == i) ? 1.0f : 0.0f;
        v.z = (i2 == i) ? 1.0f : 0.0f;
        v.w = (i3 == i) ? 1.0f : 0.0f;
        *reinterpret_cast<nfloat4*>(o) = v;   // plain cached store
        o += HWP;
    }
}

// K2: one block of 128 threads. argmax over the 10 thing-class counts
// (strict > from low class == jnp.argmax first-max; all-zero row -> class 0).
// Writes small outputs, zeroes out[SEGP] for K3's atomic accumulate, stores
// cls and 1/max(tot,1) so K3 can fold the final divide.
__global__ __launch_bounds__(128) void k2_stats(
    const int* __restrict__ counts, const float* __restrict__ iprobs,
    float* __restrict__ out, int* __restrict__ cls_ws, float* __restrict__ inv_ws)
{
    const int i = threadIdx.x;      // 0..127 -> instance id i+1
    int bestv = 0, bestc = 0, tot = 0;
    #pragma unroll
    for (int j = 0; j < NTC; ++j) {
        const int c = counts[i * NTC + j];
        tot += c;
        if (c > bestv) { bestv = c; bestc = THING_LO + j; }
    }
    cls_ws[i] = bestc;
    inv_ws[i] = 1.0f / (float)(tot > 0 ? tot : 1);
    out[OFF_CLASS + i] = (float)bestc;
    out[OFF_PROBS + i] = iprobs[i];
    out[OFF_SEGP  + i] = 0.0f;
    out[OFF_TOTAL + i] = (float)tot;
    out[OFF_VALID + i] = (tot > 0) ? 1.0f : 0.0f;
}

// K3: gather probs[cls[inst]][pix] for things-pixels; LDS-accumulate per
// block; flush pre-divided partial into out[SEGP] (k4 folded away).
__global__ __launch_bounds__(256) void k3_segsum(
    const int* __restrict__ seg, const int* __restrict__ imap,
    const float* __restrict__ probs, const int* __restrict__ cls_ws,
    const float* __restrict__ inv_ws, float* __restrict__ out)
{
    __shared__ float lsum[NI];
    __shared__ int   scls[NI];
    if (threadIdx.x < NI) {
        lsum[threadIdx.x] = 0.0f;
        scls[threadIdx.x] = cls_ws[threadIdx.x];
    }
    __syncthreads();

    const int stride = gridDim.x * blockDim.x;
    for (int t = blockIdx.x * blockDim.x + threadIdx.x; t < HWP / 4; t += stride) {
        const int p = t * 4;
        const int4 sg = *reinterpret_cast<const int4*>(seg + p);
        const int4 im = *reinterpret_cast<const int4*>(imap + p);
        const int ii[4] = { thing_inst(sg.x, im.x), thing_inst(sg.y, im.y),
                            thing_inst(sg.z, im.z), thing_inst(sg.w, im.w) };
        #pragma unroll
        for (int k = 0; k < 4; ++k) {
            if (ii[k] > 0) {
                const int inst = ii[k] - 1;
                const size_t idx = (size_t)scls[inst] * HWP + (size_t)(p + k);
                atomicAdd(&lsum[inst], probs[idx]);
            }
        }
    }
    __syncthreads();
    if (threadIdx.x < NI) {
        const float v = lsum[threadIdx.x];
        if (v != 0.0f)
            atomicAdd(&out[OFF_SEGP + threadIdx.x], v * inv_ws[threadIdx.x]);
    }
}

extern "C" void kernel_launch(void* const* d_in, const int* in_sizes, int n_in,
                              void* d_out, int out_size, void* d_ws, size_t ws_size,
                              hipStream_t stream) {
    const int*   seg    = (const int*)d_in[0];     // (H,W) int32
    const int*   imap   = (const int*)d_in[1];     // (H,W) int32
    const float* probs  = (const float*)d_in[2];   // (C,H,W) f32
    const float* iprobs = (const float*)d_in[3];   // (NI,) f32
    float* out = (float*)d_out;

    char* ws = (char*)d_ws;
    int*   counts = (int*)(ws + WS_COUNTS);
    int*   cls_ws = (int*)(ws + WS_CLS);
    float* inv_ws = (float*)(ws + WS_INV);

    (void)hipMemsetAsync(counts, 0, NI * NTC * sizeof(int), stream);

    k1_mask_count<<<(HWP / 4) / 256, 256, 0, stream>>>(seg, imap, out, counts);
    k2_stats<<<1, 128, 0, stream>>>(counts, iprobs, out, cls_ws, inv_ws);
    k3_segsum<<<256, 256, 0, stream>>>(seg, imap, probs, cls_ws, inv_ws, out);
}